// Round 12
// baseline (132.493 us; speedup 1.0000x reference)
//
#include <hip/hip_runtime.h>
#include <hip/hip_bf16.h>

constexpr int IN_CH  = 128;
constexpr int HID_CH = 128;
constexpr int OUT_CH = 64;
constexpr int SCAN_CHUNK = 1024;   // elements per scan block (256 thr x 4)

typedef __attribute__((ext_vector_type(8))) short bf16x8;
typedef __attribute__((ext_vector_type(4))) float f32x4;

// ---------------- bf16 pack/unpack helpers ----------------

__device__ inline unsigned short f2bf(float f) {
  __hip_bfloat16 h = __float2bfloat16(f);   // RN
  return *reinterpret_cast<unsigned short*>(&h);
}
__device__ inline unsigned pack_bf16x2(float lo, float hi) {
  return (unsigned)f2bf(lo) | ((unsigned)f2bf(hi) << 16);
}
__device__ inline float bf_lo(unsigned u) { return __uint_as_float(u << 16); }
__device__ inline float bf_hi(unsigned u) { return __uint_as_float(u & 0xffff0000u); }

// ---------------- workspace zeroing (cnt + lookback flags) ----------------

__global__ __launch_bounds__(256) void k_zero(int* __restrict__ a, int na,
                                              int* __restrict__ b, int nb) {
  int i = (blockIdx.x * 256 + threadIdx.x) * 4;
  if (i + 3 < na) *(int4*)&a[i] = make_int4(0, 0, 0, 0);
  else for (int j = 0; j < 4 && i + j < na; ++j) a[i + j] = 0;
  if (i + 3 < nb) *(int4*)&b[i] = make_int4(0, 0, 0, 0);
  else for (int j = 0; j < 4 && i + j < nb; ++j) b[i + j] = 0;
}

// ---------------- CSR build ----------------
// count degree AND remember each edge's slot (ord) so the fill needs no atomics.

__global__ void k_count(const int* __restrict__ dst, int* __restrict__ cnt,
                        int* __restrict__ ord, int E) {
  int e = (blockIdx.x * blockDim.x + threadIdx.x) * 4;
  if (e + 3 < E) {
    int4 v = *(const int4*)&dst[e];
    int4 o;
    o.x = atomicAdd(&cnt[v.x], 1);
    o.y = atomicAdd(&cnt[v.y], 1);
    o.z = atomicAdd(&cnt[v.z], 1);
    o.w = atomicAdd(&cnt[v.w], 1);
    *(int4*)&ord[e] = o;
  } else {
    for (int j = 0; j < 4 && e + j < E; ++j) ord[e + j] = atomicAdd(&cnt[dst[e + j]], 1);
  }
}

// Single-kernel exclusive scan (decoupled lookback) + dinv. 40 blocks, all
// co-resident; block i publishes its total (device-scope atomic after
// threadfence) and polls blocks j<i. flags zeroed each call (k_zero).
__global__ __launch_bounds__(256) void k_scan_lb(const int* __restrict__ cnt,
                                                 int* __restrict__ rowptr,
                                                 float* __restrict__ dinv,
                                                 int* __restrict__ flags,
                                                 int* __restrict__ partial,
                                                 int N, int E) {
  int t = threadIdx.x, bid = blockIdx.x;
  int base = bid * SCAN_CHUNK + t * 4;
  int v[4] = {0, 0, 0, 0};
  if (base + 3 < N) {
    int4 q = *(const int4*)&cnt[base];
    v[0] = q.x; v[1] = q.y; v[2] = q.z; v[3] = q.w;
    float4 d;
    d.x = rsqrtf((float)v[0] + 1.0f);
    d.y = rsqrtf((float)v[1] + 1.0f);
    d.z = rsqrtf((float)v[2] + 1.0f);
    d.w = rsqrtf((float)v[3] + 1.0f);
    *(float4*)&dinv[base] = d;
  } else {
    for (int j = 0; j < 4; ++j)
      if (base + j < N) {
        v[j] = cnt[base + j];
        dinv[base + j] = rsqrtf((float)v[j] + 1.0f);
      }
  }
  int mysum = v[0] + v[1] + v[2] + v[3];
  __shared__ int s[256];
  s[t] = mysum; __syncthreads();
  for (int off = 1; off < 256; off <<= 1) {
    int add = (t >= off) ? s[t - off] : 0;
    __syncthreads();
    s[t] += add;
    __syncthreads();
  }
  if (t == 255) {                       // publish block total
    partial[bid] = s[255];
    __threadfence();
    atomicExch(&flags[bid], 1);
  }
  int pv = 0;
  if (t < bid) {
    while (atomicAdd(&flags[t], 0) == 0) {}
    __threadfence();
    pv = atomicAdd(&partial[t], 0);
  }
  __shared__ int boff_s;
  if (t < 64) {
#pragma unroll
    for (int off = 32; off; off >>= 1) pv += __shfl_down(pv, off);
    if (t == 0) boff_s = pv;
  }
  __syncthreads();
  int run = boff_s + s[t] - mysum;      // exclusive prefix for my 4
  for (int j = 0; j < 4; ++j) {
    if (base + j < N) rowptr[base + j] = run;
    run += v[j];
  }
  if (bid == 0 && t == 0) rowptr[N] = E;
}

// ---------------- fused: CSR fill (blocks < nfill) || MFMA GEMM1 (rest) ----
// GEMM: Y[r][c] = bf16( (X[r,:] @ W[:,c]) * dinv[r] ), K = 128, row-major out.
// W staged to LDS as Wt[col][k] bf16, T2 XOR swizzle (byte ^= (col&7)<<4).
// MFMA 16x16x32 lane map: A: row=l&15, k=(l>>4)*8+j ; B: col=l&15, same k;
// C/D: col=l&15, row=(l>>4)*4+reg  [m89].

template <int OUT, bool A_BF16>
__device__ inline void gemm_body(int gb, const void* __restrict__ Xv,
                                 const float* __restrict__ W,
                                 const float* __restrict__ dinv,
                                 unsigned short* __restrict__ Y, int N) {
  constexpr int KD = 128;
  __shared__ unsigned short Wt[OUT * KD];  // [col][k] bf16, XOR-swizzled
  int t = threadIdx.x;
  for (int i = t * 4; i < KD * OUT; i += 1024) {
    int k = i / OUT, c = i % OUT;
    float4 w4 = *(const float4*)&W[i];
    float wa[4] = {w4.x, w4.y, w4.z, w4.w};
#pragma unroll
    for (int j = 0; j < 4; ++j) {
      int colj = c + j;
      int byte = colj * (KD * 2) + k * 2;
      byte ^= ((colj & 7) << 4);
      *(unsigned short*)((char*)Wt + byte) = f2bf(wa[j]);
    }
  }
  __syncthreads();

  int w = t >> 6, l = t & 63;
  int lr = l & 15, kg = (l >> 4) * 8;
  int r = gb * 64 + w * 16 + lr;
  bool valid = r < N;

  f32x4 acc[OUT / 16];
#pragma unroll
  for (int n = 0; n < OUT / 16; ++n) acc[n] = f32x4{0.f, 0.f, 0.f, 0.f};

#pragma unroll
  for (int kb = 0; kb < KD / 32; ++kb) {
    bf16x8 a = bf16x8{0, 0, 0, 0, 0, 0, 0, 0};
    if (valid) {
      if (A_BF16) {
        a = *(const bf16x8*)((const unsigned short*)Xv + (size_t)r * KD + kb * 32 + kg);
      } else {
        const float* xrow = (const float*)Xv + (size_t)r * KD + kb * 32 + kg;
        float4 x0 = *(const float4*)xrow;
        float4 x1 = *(const float4*)(xrow + 4);
        a[0] = (short)f2bf(x0.x); a[1] = (short)f2bf(x0.y);
        a[2] = (short)f2bf(x0.z); a[3] = (short)f2bf(x0.w);
        a[4] = (short)f2bf(x1.x); a[5] = (short)f2bf(x1.y);
        a[6] = (short)f2bf(x1.z); a[7] = (short)f2bf(x1.w);
      }
    }
#pragma unroll
    for (int n = 0; n < OUT / 16; ++n) {
      int col = n * 16 + lr;
      int byte = col * (KD * 2) + (kb * 32 + kg) * 2;
      byte ^= ((col & 7) << 4);
      bf16x8 b = *(const bf16x8*)((const char*)Wt + byte);
      acc[n] = __builtin_amdgcn_mfma_f32_16x16x32_bf16(a, b, acc[n], 0, 0, 0);
    }
  }

  int orow = gb * 64 + w * 16 + (l >> 4) * 4;
  float dn[4];
#pragma unroll
  for (int i = 0; i < 4; ++i) dn[i] = (orow + i < N) ? dinv[orow + i] : 0.f;
#pragma unroll
  for (int i = 0; i < 4; ++i) {
    if (orow + i >= N) continue;
#pragma unroll
    for (int n = 0; n < OUT / 16; ++n)
      Y[(size_t)(orow + i) * OUT + n * 16 + lr] = f2bf(acc[n][i] * dn[i]);
  }
}

template <int OUT, bool A_BF16>
__global__ __launch_bounds__(256) void k_fill_gemm(const int* __restrict__ src,
                                                   const int* __restrict__ dst,
                                                   const int* __restrict__ ord,
                                                   const int* __restrict__ rowptr,
                                                   int* __restrict__ col, int E, int nfill,
                                                   const void* __restrict__ Xv,
                                                   const float* __restrict__ W,
                                                   const float* __restrict__ dinv,
                                                   unsigned short* __restrict__ Y, int N) {
  if ((int)blockIdx.x < nfill) {
    int e0 = (blockIdx.x * 256 + threadIdx.x) * 4;
    if (e0 >= E) return;
    if (e0 + 3 < E) {
      int4 sv = *(const int4*)&src[e0];
      int4 dv = *(const int4*)&dst[e0];
      int4 ov = *(const int4*)&ord[e0];
      col[rowptr[dv.x] + ov.x] = sv.x;
      col[rowptr[dv.y] + ov.y] = sv.y;
      col[rowptr[dv.z] + ov.z] = sv.z;
      col[rowptr[dv.w] + ov.w] = sv.w;
    } else {
      for (int j = 0; j < 4 && e0 + j < E; ++j)
        col[rowptr[dst[e0 + j]] + ord[e0 + j]] = src[e0 + j];
    }
    return;
  }
  gemm_body<OUT, A_BF16>((int)blockIdx.x - nfill, Xv, W, dinv, Y, N);
}

// standalone GEMM for layer 2
template <int OUT, bool A_BF16>
__global__ __launch_bounds__(256) void k_gemm(const void* __restrict__ Xv,
                                              const float* __restrict__ W,
                                              const float* __restrict__ dinv,
                                              unsigned short* __restrict__ Y, int N) {
  gemm_body<OUT, A_BF16>((int)blockIdx.x, Xv, W, dinv, Y, N);
}

// ---------------- aggregation, 128ch bf16 table -> bf16 out (relu) --------
// uint2 gathers: 32 lanes per node, 2 nodes per wave. Masked 16-edge batches:
// no serial tail (deg<=16 nodes = ONE fully-parallel batch; mask folded into
// fmaf so the tail costs no extra VALU). Output NT-stored (hrb is only ever
// streamed by gemm2; cached stores would evict gather-table lines from L2).

__global__ __launch_bounds__(256) void k_agg128(const uint2* __restrict__ HS,
                                                const int* __restrict__ rowptr,
                                                const int* __restrict__ col,
                                                const float* __restrict__ dinv,
                                                const float* __restrict__ bias,
                                                uint2* __restrict__ Outb, int N) {
  int n = blockIdx.x * 8 + (threadIdx.x >> 5);
  if (n >= N) return;
  int c = threadIdx.x & 31;            // channels 4c..4c+3
  float dn = dinv[n];
  uint2 u0 = HS[(size_t)n * 32 + c];
  float ax = bf_lo(u0.x), ay = bf_hi(u0.x), az = bf_lo(u0.y), aw = bf_hi(u0.y);
  int p = rowptr[n], pend = rowptr[n + 1];
  while (p < pend) {
    int s[16]; float m[16];
#pragma unroll
    for (int j = 0; j < 16; ++j) {
      int q = p + j;
      int idx = q < pend ? q : pend - 1;     // clamp: pend-1 >= p valid
      s[j] = __builtin_nontemporal_load(&col[idx]);
      m[j] = q < pend ? 1.f : 0.f;
    }
    uint2 g[16];
#pragma unroll
    for (int j = 0; j < 16; ++j) g[j] = HS[(size_t)s[j] * 32 + c];
#pragma unroll
    for (int j = 0; j < 16; ++j) {
      ax = fmaf(m[j], bf_lo(g[j].x), ax);
      ay = fmaf(m[j], bf_hi(g[j].x), ay);
      az = fmaf(m[j], bf_lo(g[j].y), az);
      aw = fmaf(m[j], bf_hi(g[j].y), aw);
    }
    p += 16;
  }
  float4 b4 = ((const float4*)bias)[c];
  unsigned lo = pack_bf16x2(fmaxf(dn * ax + b4.x, 0.f), fmaxf(dn * ay + b4.y, 0.f));
  unsigned hi = pack_bf16x2(fmaxf(dn * az + b4.z, 0.f), fmaxf(dn * aw + b4.w, 0.f));
  unsigned long long pk = ((unsigned long long)hi << 32) | lo;
  __builtin_nontemporal_store(pk, (unsigned long long*)&Outb[(size_t)n * 32 + c]);
}

// ---------------- aggregation, 64ch bf16 table -> bf16 out (no relu) ------
// uint2 gathers: 16 lanes per node, 4 nodes per wave; masked 16-edge batches.
// zu is random-gathered by decode next -> keep cached stores.

__global__ __launch_bounds__(256) void k_agg64(const uint2* __restrict__ HS,
                                               const int* __restrict__ rowptr,
                                               const int* __restrict__ col,
                                               const float* __restrict__ dinv,
                                               const float* __restrict__ bias,
                                               uint2* __restrict__ Zu, int N) {
  int n = blockIdx.x * 16 + (threadIdx.x >> 4);
  if (n >= N) return;
  int c = threadIdx.x & 15;            // channels 4c..4c+3
  float dn = dinv[n];
  uint2 u0 = HS[(size_t)n * 16 + c];
  float ax = bf_lo(u0.x), ay = bf_hi(u0.x), az = bf_lo(u0.y), aw = bf_hi(u0.y);
  int p = rowptr[n], pend = rowptr[n + 1];
  while (p < pend) {
    int s[16]; float m[16];
#pragma unroll
    for (int j = 0; j < 16; ++j) {
      int q = p + j;
      int idx = q < pend ? q : pend - 1;
      s[j] = __builtin_nontemporal_load(&col[idx]);
      m[j] = q < pend ? 1.f : 0.f;
    }
    uint2 g[16];
#pragma unroll
    for (int j = 0; j < 16; ++j) g[j] = HS[(size_t)s[j] * 16 + c];
#pragma unroll
    for (int j = 0; j < 16; ++j) {
      ax = fmaf(m[j], bf_lo(g[j].x), ax);
      ay = fmaf(m[j], bf_hi(g[j].x), ay);
      az = fmaf(m[j], bf_lo(g[j].y), az);
      aw = fmaf(m[j], bf_hi(g[j].y), aw);
    }
    p += 16;
  }
  float4 b4 = ((const float4*)bias)[c];
  uint2 ov;
  ov.x = pack_bf16x2(dn * ax + b4.x, dn * ay + b4.y);
  ov.y = pack_bf16x2(dn * az + b4.z, dn * aw + b4.w);
  Zu[(size_t)n * 16 + c] = ov;
}

// ---------------- decode: logits[i] = dot(z[a[i]], z[b[i]]), z bf16 -------
// z row-major [N][32 uints] = 128 B rows; 8 lanes per pair, uint4 per lane.

__global__ __launch_bounds__(256) void k_decode(const uint4* __restrict__ Z,
                                                const int* __restrict__ ia,
                                                const int* __restrict__ ib,
                                                float* __restrict__ out, int L) {
  int t = blockIdx.x * 256 + threadIdx.x;
  int i = t >> 3;
  if (i >= L) return;
  int e = t & 7;
  int a = ia[i], b = ib[i];
  uint4 za = Z[(size_t)a * 8 + e];
  uint4 zb = Z[(size_t)b * 8 + e];
  float p = bf_lo(za.x) * bf_lo(zb.x) + bf_hi(za.x) * bf_hi(zb.x)
          + bf_lo(za.y) * bf_lo(zb.y) + bf_hi(za.y) * bf_hi(zb.y)
          + bf_lo(za.z) * bf_lo(zb.z) + bf_hi(za.z) * bf_hi(zb.z)
          + bf_lo(za.w) * bf_lo(zb.w) + bf_hi(za.w) * bf_hi(zb.w);
  p += __shfl_xor(p, 1);
  p += __shfl_xor(p, 2);
  p += __shfl_xor(p, 4);
  if (e == 0) out[i] = p;
}

extern "C" void kernel_launch(void* const* d_in, const int* in_sizes, int n_in,
                              void* d_out, int out_size, void* d_ws, size_t ws_size,
                              hipStream_t stream) {
  const float* x   = (const float*)d_in[0];
  const int*   ei  = (const int*)d_in[1];
  const int*   eli = (const int*)d_in[2];
  const float* W1  = (const float*)d_in[3];
  const float* b1  = (const float*)d_in[4];
  const float* W2  = (const float*)d_in[5];
  const float* b2  = (const float*)d_in[6];
  float* logits = (float*)d_out;

  int N = in_sizes[0] / IN_CH;
  int E = in_sizes[1] / 2;
  int L = in_sizes[2] / 2;
  const int* src = ei;
  const int* dst = ei + E;
  const int* la  = eli;
  const int* lb  = eli + L;

  char* ws = (char*)d_ws;
  size_t off = 0;
  auto alloc = [&](size_t bytes) {
    void* p = ws + off;
    off = (off + bytes + 255) & ~(size_t)255;
    return p;
  };
  int*      cnt    = (int*)alloc((size_t)N * 4);
  int*      rowptr = (int*)alloc((size_t)(N + 1) * 4);
  float*    dinv   = (float*)alloc((size_t)N * 4);
  int*      col    = (int*)alloc((size_t)E * 4);
  int*      ord    = (int*)alloc((size_t)E * 4);
  unsigned short* hs  = (unsigned short*)alloc((size_t)N * HID_CH * 2);  // bf16 h*dinv
  unsigned short* hrb = (unsigned short*)alloc((size_t)N * HID_CH * 2);  // bf16 relu out
  unsigned short* h2s = (unsigned short*)alloc((size_t)N * OUT_CH * 2);  // bf16 h2*dinv
  unsigned short* zu  = (unsigned short*)alloc((size_t)N * OUT_CH * 2);  // bf16 z
  int*      flags  = (int*)alloc(64 * 4);
  int*      partial= (int*)alloc(64 * 4);

  const int TB = 256;
  int nscan = (N + SCAN_CHUNK - 1) / SCAN_CHUNK;   // 40 blocks (co-resident)
  int nfill = (E / 4 + TB - 1) / TB;
  int ngemm = (N + 63) / 64;
  // cnt and lookback flags must be zero EVERY call
  k_zero<<<(N / 4 + TB - 1) / TB, TB, 0, stream>>>(cnt, N, flags, 64);
  k_count<<<(E / 4 + TB - 1) / TB, TB, 0, stream>>>(dst, cnt, ord, E);
  k_scan_lb<<<nscan, 256, 0, stream>>>(cnt, rowptr, dinv, flags, partial, N, E);

  // fused: CSR fill || gemm1 (independent; one dispatch)
  k_fill_gemm<HID_CH, false><<<nfill + ngemm, 256, 0, stream>>>(
      src, dst, ord, rowptr, col, E, nfill, x, W1, dinv, hs, N);

  // layer 1 aggregation: hrb = bf16(relu(dn*(self+sum) + b1))
  k_agg128<<<(N + 7) / 8, 256, 0, stream>>>(
      (const uint2*)hs, rowptr, col, dinv, b1, (uint2*)hrb, N);

  // layer 2: h2s = bf16((hrb@W2)*dinv) ; zu = bf16(dn*(self+sum) + b2)
  k_gemm<OUT_CH, true><<<ngemm, 256, 0, stream>>>(hrb, W2, dinv, h2s, N);
  k_agg64<<<(N + 15) / 16, 256, 0, stream>>>(
      (const uint2*)h2s, rowptr, col, dinv, b2, (uint2*)zu, N);

  // decode
  k_decode<<<((size_t)L * 8 + 255) / 256, 256, 0, stream>>>(
      (const uint4*)zu, la, lb, logits, L);
}

// Round 13
// 128.952 us; speedup vs baseline: 1.0275x; 1.0275x over previous
//
#include <hip/hip_runtime.h>
#include <hip/hip_bf16.h>

constexpr int IN_CH  = 128;
constexpr int HID_CH = 128;
constexpr int OUT_CH = 64;
constexpr int SCAN_CHUNK = 1024;   // elements per scan block (256 thr x 4)

typedef __attribute__((ext_vector_type(8))) short bf16x8;
typedef __attribute__((ext_vector_type(4))) float f32x4;

// ---------------- bf16 pack/unpack helpers ----------------

__device__ inline unsigned short f2bf(float f) {
  __hip_bfloat16 h = __float2bfloat16(f);   // RN
  return *reinterpret_cast<unsigned short*>(&h);
}
__device__ inline unsigned pack_bf16x2(float lo, float hi) {
  return (unsigned)f2bf(lo) | ((unsigned)f2bf(hi) << 16);
}
__device__ inline float bf_lo(unsigned u) { return __uint_as_float(u << 16); }
__device__ inline float bf_hi(unsigned u) { return __uint_as_float(u & 0xffff0000u); }

// ---------------- workspace zeroing (cnt + lookback flags) ----------------

__global__ __launch_bounds__(256) void k_zero(int* __restrict__ a, int na,
                                              int* __restrict__ b, int nb) {
  int i = (blockIdx.x * 256 + threadIdx.x) * 4;
  if (i + 3 < na) *(int4*)&a[i] = make_int4(0, 0, 0, 0);
  else for (int j = 0; j < 4 && i + j < na; ++j) a[i + j] = 0;
  if (i + 3 < nb) *(int4*)&b[i] = make_int4(0, 0, 0, 0);
  else for (int j = 0; j < 4 && i + j < nb; ++j) b[i + j] = 0;
}

// ---------------- CSR build ----------------
// count degree AND remember each edge's slot (ord) so the fill needs no atomics.

__global__ void k_count(const int* __restrict__ dst, int* __restrict__ cnt,
                        int* __restrict__ ord, int E) {
  int e = (blockIdx.x * blockDim.x + threadIdx.x) * 4;
  if (e + 3 < E) {
    int4 v = *(const int4*)&dst[e];
    int4 o;
    o.x = atomicAdd(&cnt[v.x], 1);
    o.y = atomicAdd(&cnt[v.y], 1);
    o.z = atomicAdd(&cnt[v.z], 1);
    o.w = atomicAdd(&cnt[v.w], 1);
    *(int4*)&ord[e] = o;
  } else {
    for (int j = 0; j < 4 && e + j < E; ++j) ord[e + j] = atomicAdd(&cnt[dst[e + j]], 1);
  }
}

// Single-kernel exclusive scan (decoupled lookback) + dinv. 40 blocks, all
// co-resident; block i publishes its total (device-scope atomic after
// threadfence) and polls blocks j<i. flags zeroed each call (k_zero).
__global__ __launch_bounds__(256) void k_scan_lb(const int* __restrict__ cnt,
                                                 int* __restrict__ rowptr,
                                                 float* __restrict__ dinv,
                                                 int* __restrict__ flags,
                                                 int* __restrict__ partial,
                                                 int N, int E) {
  int t = threadIdx.x, bid = blockIdx.x;
  int base = bid * SCAN_CHUNK + t * 4;
  int v[4] = {0, 0, 0, 0};
  if (base + 3 < N) {
    int4 q = *(const int4*)&cnt[base];
    v[0] = q.x; v[1] = q.y; v[2] = q.z; v[3] = q.w;
    float4 d;
    d.x = rsqrtf((float)v[0] + 1.0f);
    d.y = rsqrtf((float)v[1] + 1.0f);
    d.z = rsqrtf((float)v[2] + 1.0f);
    d.w = rsqrtf((float)v[3] + 1.0f);
    *(float4*)&dinv[base] = d;
  } else {
    for (int j = 0; j < 4; ++j)
      if (base + j < N) {
        v[j] = cnt[base + j];
        dinv[base + j] = rsqrtf((float)v[j] + 1.0f);
      }
  }
  int mysum = v[0] + v[1] + v[2] + v[3];
  __shared__ int s[256];
  s[t] = mysum; __syncthreads();
  for (int off = 1; off < 256; off <<= 1) {
    int add = (t >= off) ? s[t - off] : 0;
    __syncthreads();
    s[t] += add;
    __syncthreads();
  }
  if (t == 255) {                       // publish block total
    partial[bid] = s[255];
    __threadfence();
    atomicExch(&flags[bid], 1);
  }
  int pv = 0;
  if (t < bid) {
    while (atomicAdd(&flags[t], 0) == 0) {}
    __threadfence();
    pv = atomicAdd(&partial[t], 0);
  }
  __shared__ int boff_s;
  if (t < 64) {
#pragma unroll
    for (int off = 32; off; off >>= 1) pv += __shfl_down(pv, off);
    if (t == 0) boff_s = pv;
  }
  __syncthreads();
  int run = boff_s + s[t] - mysum;      // exclusive prefix for my 4
  for (int j = 0; j < 4; ++j) {
    if (base + j < N) rowptr[base + j] = run;
    run += v[j];
  }
  if (bid == 0 && t == 0) rowptr[N] = E;
}

// ---------------- fused: CSR fill (blocks < nfill) || MFMA GEMM1 (rest) ----
// GEMM: Y[r][c] = bf16( (X[r,:] @ W[:,c]) * dinv[r] ), K = 128, row-major out.
// W staged to LDS as Wt[col][k] bf16, T2 XOR swizzle (byte ^= (col&7)<<4).
// MFMA 16x16x32 lane map: A: row=l&15, k=(l>>4)*8+j ; B: col=l&15, same k;
// C/D: col=l&15, row=(l>>4)*4+reg  [m89].

template <int OUT, bool A_BF16>
__device__ inline void gemm_body(int gb, const void* __restrict__ Xv,
                                 const float* __restrict__ W,
                                 const float* __restrict__ dinv,
                                 unsigned short* __restrict__ Y, int N) {
  constexpr int KD = 128;
  __shared__ unsigned short Wt[OUT * KD];  // [col][k] bf16, XOR-swizzled
  int t = threadIdx.x;
  for (int i = t * 4; i < KD * OUT; i += 1024) {
    int k = i / OUT, c = i % OUT;
    float4 w4 = *(const float4*)&W[i];
    float wa[4] = {w4.x, w4.y, w4.z, w4.w};
#pragma unroll
    for (int j = 0; j < 4; ++j) {
      int colj = c + j;
      int byte = colj * (KD * 2) + k * 2;
      byte ^= ((colj & 7) << 4);
      *(unsigned short*)((char*)Wt + byte) = f2bf(wa[j]);
    }
  }
  __syncthreads();

  int w = t >> 6, l = t & 63;
  int lr = l & 15, kg = (l >> 4) * 8;
  int r = gb * 64 + w * 16 + lr;
  bool valid = r < N;

  f32x4 acc[OUT / 16];
#pragma unroll
  for (int n = 0; n < OUT / 16; ++n) acc[n] = f32x4{0.f, 0.f, 0.f, 0.f};

#pragma unroll
  for (int kb = 0; kb < KD / 32; ++kb) {
    bf16x8 a = bf16x8{0, 0, 0, 0, 0, 0, 0, 0};
    if (valid) {
      if (A_BF16) {
        a = *(const bf16x8*)((const unsigned short*)Xv + (size_t)r * KD + kb * 32 + kg);
      } else {
        const float* xrow = (const float*)Xv + (size_t)r * KD + kb * 32 + kg;
        float4 x0 = *(const float4*)xrow;
        float4 x1 = *(const float4*)(xrow + 4);
        a[0] = (short)f2bf(x0.x); a[1] = (short)f2bf(x0.y);
        a[2] = (short)f2bf(x0.z); a[3] = (short)f2bf(x0.w);
        a[4] = (short)f2bf(x1.x); a[5] = (short)f2bf(x1.y);
        a[6] = (short)f2bf(x1.z); a[7] = (short)f2bf(x1.w);
      }
    }
#pragma unroll
    for (int n = 0; n < OUT / 16; ++n) {
      int col = n * 16 + lr;
      int byte = col * (KD * 2) + (kb * 32 + kg) * 2;
      byte ^= ((col & 7) << 4);
      bf16x8 b = *(const bf16x8*)((const char*)Wt + byte);
      acc[n] = __builtin_amdgcn_mfma_f32_16x16x32_bf16(a, b, acc[n], 0, 0, 0);
    }
  }

  int orow = gb * 64 + w * 16 + (l >> 4) * 4;
  float dn[4];
#pragma unroll
  for (int i = 0; i < 4; ++i) dn[i] = (orow + i < N) ? dinv[orow + i] : 0.f;
#pragma unroll
  for (int i = 0; i < 4; ++i) {
    if (orow + i >= N) continue;
#pragma unroll
    for (int n = 0; n < OUT / 16; ++n)
      Y[(size_t)(orow + i) * OUT + n * 16 + lr] = f2bf(acc[n][i] * dn[i]);
  }
}

template <int OUT, bool A_BF16>
__global__ __launch_bounds__(256) void k_fill_gemm(const int* __restrict__ src,
                                                   const int* __restrict__ dst,
                                                   const int* __restrict__ ord,
                                                   const int* __restrict__ rowptr,
                                                   int* __restrict__ col, int E, int nfill,
                                                   const void* __restrict__ Xv,
                                                   const float* __restrict__ W,
                                                   const float* __restrict__ dinv,
                                                   unsigned short* __restrict__ Y, int N) {
  if ((int)blockIdx.x < nfill) {
    int e0 = (blockIdx.x * 256 + threadIdx.x) * 4;
    if (e0 >= E) return;
    if (e0 + 3 < E) {
      int4 sv = *(const int4*)&src[e0];
      int4 dv = *(const int4*)&dst[e0];
      int4 ov = *(const int4*)&ord[e0];
      col[rowptr[dv.x] + ov.x] = sv.x;
      col[rowptr[dv.y] + ov.y] = sv.y;
      col[rowptr[dv.z] + ov.z] = sv.z;
      col[rowptr[dv.w] + ov.w] = sv.w;
    } else {
      for (int j = 0; j < 4 && e0 + j < E; ++j)
        col[rowptr[dst[e0 + j]] + ord[e0 + j]] = src[e0 + j];
    }
    return;
  }
  gemm_body<OUT, A_BF16>((int)blockIdx.x - nfill, Xv, W, dinv, Y, N);
}

// standalone GEMM for layer 2
template <int OUT, bool A_BF16>
__global__ __launch_bounds__(256) void k_gemm(const void* __restrict__ Xv,
                                              const float* __restrict__ W,
                                              const float* __restrict__ dinv,
                                              unsigned short* __restrict__ Y, int N) {
  gemm_body<OUT, A_BF16>((int)blockIdx.x, Xv, W, dinv, Y, N);
}

// ---------------- aggregation, 128ch bf16 table -> bf16 out (relu) --------
// uint2 gathers: 32 lanes per node (8 B/lane = 256 B row), 2 nodes per wave.
// 8/4/1-deep gather pipeline (R12's masked 16-batch regressed: clamped
// duplicate gathers add line traffic on a line-bound kernel). Cached stores
// (R12's NT store regressed: gemm2 re-reads hrb).

__global__ __launch_bounds__(256) void k_agg128(const uint2* __restrict__ HS,
                                                const int* __restrict__ rowptr,
                                                const int* __restrict__ col,
                                                const float* __restrict__ dinv,
                                                const float* __restrict__ bias,
                                                uint2* __restrict__ Outb, int N) {
  int n = blockIdx.x * 8 + (threadIdx.x >> 5);
  if (n >= N) return;
  int c = threadIdx.x & 31;            // channels 4c..4c+3
  float dn = dinv[n];
  uint2 u0 = HS[(size_t)n * 32 + c];
  float ax = bf_lo(u0.x), ay = bf_hi(u0.x), az = bf_lo(u0.y), aw = bf_hi(u0.y);
  int p = rowptr[n], pend = rowptr[n + 1];
  for (; p + 8 <= pend; p += 8) {
    int s[8]; uint2 g[8];
#pragma unroll
    for (int j = 0; j < 8; ++j) s[j] = __builtin_nontemporal_load(&col[p + j]);
#pragma unroll
    for (int j = 0; j < 8; ++j) g[j] = HS[(size_t)s[j] * 32 + c];
#pragma unroll
    for (int j = 0; j < 8; ++j) {
      ax += bf_lo(g[j].x); ay += bf_hi(g[j].x);
      az += bf_lo(g[j].y); aw += bf_hi(g[j].y);
    }
  }
  if (p + 4 <= pend) {
    int s[4]; uint2 g[4];
#pragma unroll
    for (int j = 0; j < 4; ++j) s[j] = __builtin_nontemporal_load(&col[p + j]);
#pragma unroll
    for (int j = 0; j < 4; ++j) g[j] = HS[(size_t)s[j] * 32 + c];
#pragma unroll
    for (int j = 0; j < 4; ++j) {
      ax += bf_lo(g[j].x); ay += bf_hi(g[j].x);
      az += bf_lo(g[j].y); aw += bf_hi(g[j].y);
    }
    p += 4;
  }
  for (; p < pend; ++p) {
    uint2 g = HS[(size_t)__builtin_nontemporal_load(&col[p]) * 32 + c];
    ax += bf_lo(g.x); ay += bf_hi(g.x); az += bf_lo(g.y); aw += bf_hi(g.y);
  }
  float4 b4 = ((const float4*)bias)[c];
  uint2 ov;
  ov.x = pack_bf16x2(fmaxf(dn * ax + b4.x, 0.f), fmaxf(dn * ay + b4.y, 0.f));
  ov.y = pack_bf16x2(fmaxf(dn * az + b4.z, 0.f), fmaxf(dn * aw + b4.w, 0.f));
  Outb[(size_t)n * 32 + c] = ov;
}

// ---------------- aggregation, 64ch bf16 table -> bf16 out (no relu) ------
// uint2 gathers: 16 lanes per node (128 B row), 4 nodes per wave.

__global__ __launch_bounds__(256) void k_agg64(const uint2* __restrict__ HS,
                                               const int* __restrict__ rowptr,
                                               const int* __restrict__ col,
                                               const float* __restrict__ dinv,
                                               const float* __restrict__ bias,
                                               uint2* __restrict__ Zu, int N) {
  int n = blockIdx.x * 16 + (threadIdx.x >> 4);
  if (n >= N) return;
  int c = threadIdx.x & 15;            // channels 4c..4c+3
  float dn = dinv[n];
  uint2 u0 = HS[(size_t)n * 16 + c];
  float ax = bf_lo(u0.x), ay = bf_hi(u0.x), az = bf_lo(u0.y), aw = bf_hi(u0.y);
  int p = rowptr[n], pend = rowptr[n + 1];
  for (; p + 8 <= pend; p += 8) {
    int s[8]; uint2 g[8];
#pragma unroll
    for (int j = 0; j < 8; ++j) s[j] = __builtin_nontemporal_load(&col[p + j]);
#pragma unroll
    for (int j = 0; j < 8; ++j) g[j] = HS[(size_t)s[j] * 16 + c];
#pragma unroll
    for (int j = 0; j < 8; ++j) {
      ax += bf_lo(g[j].x); ay += bf_hi(g[j].x);
      az += bf_lo(g[j].y); aw += bf_hi(g[j].y);
    }
  }
  if (p + 4 <= pend) {
    int s[4]; uint2 g[4];
#pragma unroll
    for (int j = 0; j < 4; ++j) s[j] = __builtin_nontemporal_load(&col[p + j]);
#pragma unroll
    for (int j = 0; j < 4; ++j) g[j] = HS[(size_t)s[j] * 16 + c];
#pragma unroll
    for (int j = 0; j < 4; ++j) {
      ax += bf_lo(g[j].x); ay += bf_hi(g[j].x);
      az += bf_lo(g[j].y); aw += bf_hi(g[j].y);
    }
    p += 4;
  }
  for (; p < pend; ++p) {
    uint2 g = HS[(size_t)__builtin_nontemporal_load(&col[p]) * 16 + c];
    ax += bf_lo(g.x); ay += bf_hi(g.x); az += bf_lo(g.y); aw += bf_hi(g.y);
  }
  float4 b4 = ((const float4*)bias)[c];
  uint2 ov;
  ov.x = pack_bf16x2(dn * ax + b4.x, dn * ay + b4.y);
  ov.y = pack_bf16x2(dn * az + b4.z, dn * aw + b4.w);
  Zu[(size_t)n * 16 + c] = ov;
}

// ---------------- decode: logits[i] = dot(z[a[i]], z[b[i]]), z bf16 -------
// z row-major [N][32 uints] = 128 B rows; 8 lanes per pair, uint4 per lane.

__global__ __launch_bounds__(256) void k_decode(const uint4* __restrict__ Z,
                                                const int* __restrict__ ia,
                                                const int* __restrict__ ib,
                                                float* __restrict__ out, int L) {
  int t = blockIdx.x * 256 + threadIdx.x;
  int i = t >> 3;
  if (i >= L) return;
  int e = t & 7;
  int a = ia[i], b = ib[i];
  uint4 za = Z[(size_t)a * 8 + e];
  uint4 zb = Z[(size_t)b * 8 + e];
  float p = bf_lo(za.x) * bf_lo(zb.x) + bf_hi(za.x) * bf_hi(zb.x)
          + bf_lo(za.y) * bf_lo(zb.y) + bf_hi(za.y) * bf_hi(zb.y)
          + bf_lo(za.z) * bf_lo(zb.z) + bf_hi(za.z) * bf_hi(zb.z)
          + bf_lo(za.w) * bf_lo(zb.w) + bf_hi(za.w) * bf_hi(zb.w);
  p += __shfl_xor(p, 1);
  p += __shfl_xor(p, 2);
  p += __shfl_xor(p, 4);
  if (e == 0) out[i] = p;
}

extern "C" void kernel_launch(void* const* d_in, const int* in_sizes, int n_in,
                              void* d_out, int out_size, void* d_ws, size_t ws_size,
                              hipStream_t stream) {
  const float* x   = (const float*)d_in[0];
  const int*   ei  = (const int*)d_in[1];
  const int*   eli = (const int*)d_in[2];
  const float* W1  = (const float*)d_in[3];
  const float* b1  = (const float*)d_in[4];
  const float* W2  = (const float*)d_in[5];
  const float* b2  = (const float*)d_in[6];
  float* logits = (float*)d_out;

  int N = in_sizes[0] / IN_CH;
  int E = in_sizes[1] / 2;
  int L = in_sizes[2] / 2;
  const int* src = ei;
  const int* dst = ei + E;
  const int* la  = eli;
  const int* lb  = eli + L;

  char* ws = (char*)d_ws;
  size_t off = 0;
  auto alloc = [&](size_t bytes) {
    void* p = ws + off;
    off = (off + bytes + 255) & ~(size_t)255;
    return p;
  };
  int*      cnt    = (int*)alloc((size_t)N * 4);
  int*      rowptr = (int*)alloc((size_t)(N + 1) * 4);
  float*    dinv   = (float*)alloc((size_t)N * 4);
  int*      col    = (int*)alloc((size_t)E * 4);
  int*      ord    = (int*)alloc((size_t)E * 4);
  unsigned short* hs  = (unsigned short*)alloc((size_t)N * HID_CH * 2);  // bf16 h*dinv
  unsigned short* hrb = (unsigned short*)alloc((size_t)N * HID_CH * 2);  // bf16 relu out
  unsigned short* h2s = (unsigned short*)alloc((size_t)N * OUT_CH * 2);  // bf16 h2*dinv
  unsigned short* zu  = (unsigned short*)alloc((size_t)N * OUT_CH * 2);  // bf16 z
  int*      flags  = (int*)alloc(64 * 4);
  int*      partial= (int*)alloc(64 * 4);

  const int TB = 256;
  int nscan = (N + SCAN_CHUNK - 1) / SCAN_CHUNK;   // 40 blocks (co-resident)
  int nfill = (E / 4 + TB - 1) / TB;
  int ngemm = (N + 63) / 64;
  // cnt and lookback flags must be zero EVERY call
  k_zero<<<(N / 4 + TB - 1) / TB, TB, 0, stream>>>(cnt, N, flags, 64);
  k_count<<<(E / 4 + TB - 1) / TB, TB, 0, stream>>>(dst, cnt, ord, E);
  k_scan_lb<<<nscan, 256, 0, stream>>>(cnt, rowptr, dinv, flags, partial, N, E);

  // fused: CSR fill || gemm1 (independent; one dispatch)
  k_fill_gemm<HID_CH, false><<<nfill + ngemm, 256, 0, stream>>>(
      src, dst, ord, rowptr, col, E, nfill, x, W1, dinv, hs, N);

  // layer 1 aggregation: hrb = bf16(relu(dn*(self+sum) + b1))
  k_agg128<<<(N + 7) / 8, 256, 0, stream>>>(
      (const uint2*)hs, rowptr, col, dinv, b1, (uint2*)hrb, N);

  // layer 2: h2s = bf16((hrb@W2)*dinv) ; zu = bf16(dn*(self+sum) + b2)
  k_gemm<OUT_CH, true><<<ngemm, 256, 0, stream>>>(hrb, W2, dinv, h2s, N);
  k_agg64<<<(N + 15) / 16, 256, 0, stream>>>(
      (const uint2*)h2s, rowptr, col, dinv, b2, (uint2*)zu, N);

  // decode
  k_decode<<<((size_t)L * 8 + 255) / 256, 256, 0, stream>>>(
      (const uint4*)zu, la, lb, logits, L);
}